// Round 4
// baseline (160.570 us; speedup 1.0000x reference)
//
#include <hip/hip_runtime.h>
#include <stdint.h>

// MPS chain contraction, B=32768, L=256, D=16 — bidirectional split +
// permutation-absorbed B layout (no cross-lane ops in the chain).
//
// out = v0^T M_0 .. M_253 z = f . b ; fwd 128 steps, bwd 126 steps.
// Step GEMM (16x16x32): C[m][n] = sum_k A_p[m][k] * B[k][n], n = sample.
// C/D layout gives lane (g,n) rows 4g..4g+3. We DEFINE the B K-mapping as
//   k = 8g + j :  j<4 -> hi(row 4g+j),  j>=4 -> lo(row 4g+j-4)
// so the next B operand is built per-lane from the accumulator (and/sub/perm
// only). The A table is built with the same scrambled K. Exact product:
//   A_main = [ch@hi-pos, cl@lo-pos];  A_main x B  = ch*vh + cl*vl
//   A_main x Bswap(dwords {2,3,0,1}) = ch*vl + cl*vh   -> sum is exact.

typedef short  bf16x8 __attribute__((ext_vector_type(8)));
typedef float  f32x4  __attribute__((ext_vector_type(4)));
typedef int    i32x4  __attribute__((ext_vector_type(4)));
typedef unsigned int u32;

#define NFWD 128
#define NBWD 126
#define BWD_OFF (NFWD*2*64)

// result = (hi & 0xFFFF0000) | (lo >> 16)
#define PACK_HI(hi, lo) ((int)__builtin_amdgcn_perm((u32)(hi), (u32)(lo), 0x07060302u))

__device__ __forceinline__ u32 rne_bump(u32 u){
  return u + 0x7FFFu + ((u >> 16) & 1u);
}

// fragment f=p per step; lane (m=lane&15, g=lane>>4) holds k=8g+j, j=0..7,
// dword d = (j=2d low16, j=2d+1 high16). q = 4g + (j&3), hi part iff j<4.
// fwd: c_p[m][q] = cm[t][q][p][m] ; bwd: c_p[m][q] = cm[t][m][p][q].
__global__ void build_frags(const float* __restrict__ cm, i32x4* __restrict__ ws)
{
  const int bid  = blockIdx.x;          // 0..127 fwd, 128..253 bwd
  const int p    = threadIdx.x >> 6;    // block = 128 threads
  const int lane = threadIdx.x & 63;
  const int m    = lane & 15;
  const int g    = lane >> 4;
  const bool fwd = bid < NFWD;
  const int slot = fwd ? bid : (bid - NFWD);
  const int t    = fwd ? bid : (253 - slot);
  i32x4* dst = ws + (fwd ? 0 : BWD_OFF) + (slot*2 + p)*64 + lane;
  i32x4 w;
  #pragma unroll
  for(int d=0; d<4; ++d){
    u32 h[2];
    #pragma unroll
    for(int e=0; e<2; ++e){
      const int j = 2*d + e;
      const int q = 4*g + (j & 3);
      const bool hi_part = (j < 4);
      const int ci = fwd ? ((((t*16 + q)*2) + p)*16 + m)
                         : ((((t*16 + m)*2) + p)*16 + q);
      const float c = cm[ci];
      const u32 u  = __float_as_uint(c);
      const u32 a  = rne_bump(u);
      const float hif = __uint_as_float(a & 0xFFFF0000u);
      const u32 b  = rne_bump(__float_as_uint(c - hif));
      h[e] = hi_part ? (a >> 16) : (b >> 16);
    }
    w[d] = (int)(h[0] | (h[1] << 16));
  }
  *dst = w;
}

__global__ __launch_bounds__(256) void mps_chain(
  const float* __restrict__ phi,
  const float* __restrict__ core_first,
  const float* __restrict__ core_last,
  const float* __restrict__ bias,
  const i32x4* __restrict__ ws,
  float* __restrict__ out)
{
  const int lane = threadIdx.x & 63;
  const int wv   = threadIdx.x >> 6;
  const int b0   = blockIdx.x * 32;
  const int n    = lane & 15;              // sample column
  const int g    = lane >> 4;              // holds rows 4g..4g+3
  const int s_in = (wv & 1)*16 + n;
  const bool isFwd = (wv < 2);

  const float* phiRow = phi + (size_t)(b0 + s_in) * 512;

  __shared__ float red[2][32][20];

  float v[4];
  i32x4 bfr;

  // per-lane truncation hi/lo split straight into B-operand registers
  auto make_bfrag = [&](){
    const u32 u0 = __float_as_uint(v[0]), u1 = __float_as_uint(v[1]);
    const u32 u2 = __float_as_uint(v[2]), u3 = __float_as_uint(v[3]);
    const float l0 = v[0] - __uint_as_float(u0 & 0xFFFF0000u);
    const float l1 = v[1] - __uint_as_float(u1 & 0xFFFF0000u);
    const float l2 = v[2] - __uint_as_float(u2 & 0xFFFF0000u);
    const float l3 = v[3] - __uint_as_float(u3 & 0xFFFF0000u);
    bfr[0] = PACK_HI(u1, u0);                                      // hi0,hi1
    bfr[1] = PACK_HI(u3, u2);                                      // hi2,hi3
    bfr[2] = PACK_HI(__float_as_uint(l1), __float_as_uint(l0));    // lo0,lo1
    bfr[3] = PACK_HI(__float_as_uint(l3), __float_as_uint(l2));    // lo2,lo3
  };

  auto step = [&](const i32x4& a0, const i32x4& a1, float phx, float phy){
    i32x4 sw; sw[0]=bfr[2]; sw[1]=bfr[3]; sw[2]=bfr[0]; sw[3]=bfr[1];
    const bf16x8 bh = __builtin_bit_cast(bf16x8, bfr);
    const bf16x8 bs = __builtin_bit_cast(bf16x8, sw);
    f32x4 acc0 = {0.f,0.f,0.f,0.f};
    f32x4 acc1 = {0.f,0.f,0.f,0.f};
    acc0 = __builtin_amdgcn_mfma_f32_16x16x32_bf16(__builtin_bit_cast(bf16x8, a0), bh, acc0, 0,0,0);
    acc0 = __builtin_amdgcn_mfma_f32_16x16x32_bf16(__builtin_bit_cast(bf16x8, a0), bs, acc0, 0,0,0);
    acc1 = __builtin_amdgcn_mfma_f32_16x16x32_bf16(__builtin_bit_cast(bf16x8, a1), bh, acc1, 0,0,0);
    acc1 = __builtin_amdgcn_mfma_f32_16x16x32_bf16(__builtin_bit_cast(bf16x8, a1), bs, acc1, 0,0,0);
    v[0] = phx*acc0[0] + phy*acc1[0];
    v[1] = phx*acc0[1] + phy*acc1[1];
    v[2] = phx*acc0[2] + phy*acc1[2];
    v[3] = phx*acc0[3] + phy*acc1[3];
    make_bfrag();
  };

  if (isFwd){
    const i32x4* tab = ws;
    const float2 ph0 = *(const float2*)phiRow;    // phi[0]
    #pragma unroll
    for(int reg=0; reg<4; ++reg){
      const int r = g*4 + reg;
      v[reg] = ph0.x * core_first[r] + ph0.y * core_first[16 + r];
    }
    make_bfrag();
    i32x4 F0a = tab[lane],       F0b = tab[64 + lane];
    i32x4 F1a = tab[128 + lane], F1b = tab[192 + lane];
    i32x4 F2a = tab[256 + lane], F2b = tab[320 + lane];
    i32x4 F3a = tab[384 + lane], F3b = tab[448 + lane];
    float2 c0 = *(const float2*)(phiRow + 2);     // coeff(t) = phi[t+1]
    float2 c1 = *(const float2*)(phiRow + 4);
    float2 c2 = *(const float2*)(phiRow + 6);
    float2 c3 = *(const float2*)(phiRow + 8);
    #pragma unroll 1
    for(int t = 0; t < NFWD; t += 4){
      step(F0a, F0b, c0.x, c0.y);
      { const int sp = (t+4 < NFWD) ? (t+4) : (NFWD-1);
        F0a = tab[sp*128 + lane]; F0b = tab[sp*128 + 64 + lane];
        c0 = *(const float2*)(phiRow + 2*(t+5)); }
      step(F1a, F1b, c1.x, c1.y);
      { const int sp = (t+5 < NFWD) ? (t+5) : (NFWD-1);
        F1a = tab[sp*128 + lane]; F1b = tab[sp*128 + 64 + lane];
        c1 = *(const float2*)(phiRow + 2*(t+6)); }
      step(F2a, F2b, c2.x, c2.y);
      { const int sp = (t+6 < NFWD) ? (t+6) : (NFWD-1);
        F2a = tab[sp*128 + lane]; F2b = tab[sp*128 + 64 + lane];
        c2 = *(const float2*)(phiRow + 2*(t+7)); }
      step(F3a, F3b, c3.x, c3.y);
      { const int sp = (t+7 < NFWD) ? (t+7) : (NFWD-1);
        F3a = tab[sp*128 + lane]; F3b = tab[sp*128 + 64 + lane];
        c3 = *(const float2*)(phiRow + 2*(t+8)); }
    }
  } else {
    const i32x4* tab = ws + BWD_OFF;
    const float4 fL = *(const float4*)(phiRow + 508);  // idx254 (x,y) idx255 (z,w)
    #pragma unroll
    for(int reg=0; reg<4; ++reg){
      const int r = g*4 + reg;
      v[reg] = fL.z * core_last[2*r] + fL.w * core_last[2*r + 1];
    }
    make_bfrag();
    i32x4 F0a = tab[lane],       F0b = tab[64 + lane];
    i32x4 F1a = tab[128 + lane], F1b = tab[192 + lane];
    i32x4 F2a = tab[256 + lane], F2b = tab[320 + lane];
    i32x4 F3a = tab[384 + lane], F3b = tab[448 + lane];
    float2 c0 = make_float2(fL.x, fL.y);               // coeff(s) = phi[254-s]
    float2 c1 = *(const float2*)(phiRow + 2*253);
    float2 c2 = *(const float2*)(phiRow + 2*252);
    float2 c3 = *(const float2*)(phiRow + 2*251);
    #pragma unroll 1
    for(int s = 0; s < 124; s += 4){
      step(F0a, F0b, c0.x, c0.y);
      { const int sp = (s+4 < NBWD) ? (s+4) : (NBWD-1);
        F0a = tab[sp*128 + lane]; F0b = tab[sp*128 + 64 + lane];
        c0 = *(const float2*)(phiRow + 2*(250-s)); }
      step(F1a, F1b, c1.x, c1.y);
      { const int sp = (s+5 < NBWD) ? (s+5) : (NBWD-1);
        F1a = tab[sp*128 + lane]; F1b = tab[sp*128 + 64 + lane];
        c1 = *(const float2*)(phiRow + 2*(249-s)); }
      step(F2a, F2b, c2.x, c2.y);
      { const int sp = (s+6 < NBWD) ? (s+6) : (NBWD-1);
        F2a = tab[sp*128 + lane]; F2b = tab[sp*128 + 64 + lane];
        c2 = *(const float2*)(phiRow + 2*(248-s)); }
      step(F3a, F3b, c3.x, c3.y);
      { const int sp = (s+7 < NBWD) ? (s+7) : (NBWD-1);
        F3a = tab[sp*128 + lane]; F3b = tab[sp*128 + 64 + lane];
        c3 = *(const float2*)(phiRow + 2*(247-s)); }
    }
    step(F0a, F0b, c0.x, c0.y);   // s=124
    step(F1a, F1b, c1.x, c1.y);   // s=125
  }

  // epilogue: deposit f / b, block dot
  *(float4*)&red[isFwd ? 0 : 1][s_in][4*g] = make_float4(v[0], v[1], v[2], v[3]);
  __syncthreads();
  if (threadIdx.x < 32){
    const int s = threadIdx.x;
    float acc = bias[0];
    #pragma unroll
    for(int q = 0; q < 16; ++q)
      acc += red[0][s][q] * red[1][s][q];
    out[b0 + s] = acc;
  }
}

extern "C" void kernel_launch(void* const* d_in, const int* in_sizes, int n_in,
                              void* d_out, int out_size, void* d_ws, size_t ws_size,
                              hipStream_t stream)
{
  const float* phi  = (const float*)d_in[0];  // [32768,256,2]
  const float* cf   = (const float*)d_in[1];  // [2,16]
  const float* cm   = (const float*)d_in[2];  // [254,16,2,16]
  const float* cl   = (const float*)d_in[3];  // [16,2]
  const float* bias = (const float*)d_in[4];  // scalar
  i32x4* ws = (i32x4*)d_ws;                   // (128+126)*2*64*16B = 508 KB

  build_frags<<<254, 128, 0, stream>>>(cm, ws);
  mps_chain<<<1024, 256, 0, stream>>>(phi, cf, cl, bias, ws, (float*)d_out);
}

// Round 5
// 160.041 us; speedup vs baseline: 1.0033x; 1.0033x over previous
//
#include <hip/hip_runtime.h>
#include <stdint.h>

// MPS chain contraction, B=32768, L=256, D=16 — bidirectional split +
// permutation-absorbed B layout (no cross-lane ops in the chain).
//
// out = v0^T M_0 .. M_253 z = f . b ; fwd 128 steps, bwd 126 steps.
// Step GEMM (16x16x32): C[m][n] = sum_k A_p[m][k] * B[k][n], n = sample.
// C/D layout gives lane (g,n) rows 4g..4g+3. We DEFINE the B K-mapping as
//   k = 8g + j :  j<4 -> hi(row 4g+j),  j>=4 -> lo(row 4g+j-4)
// so the next B operand is built per-lane from the accumulator (and/sub/perm
// only). The A table is built with the same scrambled K. Exact product:
//   A_main = [ch@hi-pos, cl@lo-pos];  A_main x B  = ch*vh + cl*vl
//   A_main x Bswap(dwords {2,3,0,1}) = ch*vl + cl*vh   -> sum is exact.
//
// R5: __launch_bounds__(256,4) -> VGPR budget 128 so the distance-4 register
// prefetch pipeline SURVIVES (R2-R4 collapsed to load-at-use at VGPR<=40,
// exposing ~500-900cyc L2/L3 latency per step — the real binder).

typedef short  bf16x8 __attribute__((ext_vector_type(8)));
typedef float  f32x4  __attribute__((ext_vector_type(4)));
typedef int    i32x4  __attribute__((ext_vector_type(4)));
typedef unsigned int u32;

#define NFWD 128
#define NBWD 126
#define BWD_OFF (NFWD*2*64)

// result = (hi & 0xFFFF0000) | (lo >> 16)
#define PACK_HI(hi, lo) ((int)__builtin_amdgcn_perm((u32)(hi), (u32)(lo), 0x07060302u))

__device__ __forceinline__ u32 rne_bump(u32 u){
  return u + 0x7FFFu + ((u >> 16) & 1u);
}

// fragment f=p per step; lane (m=lane&15, g=lane>>4) holds k=8g+j, j=0..7,
// dword d = (j=2d low16, j=2d+1 high16). q = 4g + (j&3), hi part iff j<4.
// fwd: c_p[m][q] = cm[t][q][p][m] ; bwd: c_p[m][q] = cm[t][m][p][q].
__global__ void build_frags(const float* __restrict__ cm, i32x4* __restrict__ ws)
{
  const int bid  = blockIdx.x;          // 0..127 fwd, 128..253 bwd
  const int p    = threadIdx.x >> 6;    // block = 128 threads
  const int lane = threadIdx.x & 63;
  const int m    = lane & 15;
  const int g    = lane >> 4;
  const bool fwd = bid < NFWD;
  const int slot = fwd ? bid : (bid - NFWD);
  const int t    = fwd ? bid : (253 - slot);
  i32x4* dst = ws + (fwd ? 0 : BWD_OFF) + (slot*2 + p)*64 + lane;
  i32x4 w;
  #pragma unroll
  for(int d=0; d<4; ++d){
    u32 h[2];
    #pragma unroll
    for(int e=0; e<2; ++e){
      const int j = 2*d + e;
      const int q = 4*g + (j & 3);
      const bool hi_part = (j < 4);
      const int ci = fwd ? ((((t*16 + q)*2) + p)*16 + m)
                         : ((((t*16 + m)*2) + p)*16 + q);
      const float c = cm[ci];
      const u32 u  = __float_as_uint(c);
      const u32 a  = rne_bump(u);
      const float hif = __uint_as_float(a & 0xFFFF0000u);
      const u32 b  = rne_bump(__float_as_uint(c - hif));
      h[e] = hi_part ? (a >> 16) : (b >> 16);
    }
    w[d] = (int)(h[0] | (h[1] << 16));
  }
  *dst = w;
}

__global__ __launch_bounds__(256, 4) void mps_chain(
  const float* __restrict__ phi,
  const float* __restrict__ core_first,
  const float* __restrict__ core_last,
  const float* __restrict__ bias,
  const i32x4* __restrict__ ws,
  float* __restrict__ out)
{
  const int lane = threadIdx.x & 63;
  const int wv   = threadIdx.x >> 6;
  const int b0   = blockIdx.x * 32;
  const int n    = lane & 15;              // sample column
  const int g    = lane >> 4;              // holds rows 4g..4g+3
  const int s_in = (wv & 1)*16 + n;
  const bool isFwd = (wv < 2);

  const float* phiRow = phi + (size_t)(b0 + s_in) * 512;

  __shared__ float red[2][32][20];

  float v[4];
  i32x4 bfr;

  // per-lane truncation hi/lo split straight into B-operand registers
  auto make_bfrag = [&](){
    const u32 u0 = __float_as_uint(v[0]), u1 = __float_as_uint(v[1]);
    const u32 u2 = __float_as_uint(v[2]), u3 = __float_as_uint(v[3]);
    const float l0 = v[0] - __uint_as_float(u0 & 0xFFFF0000u);
    const float l1 = v[1] - __uint_as_float(u1 & 0xFFFF0000u);
    const float l2 = v[2] - __uint_as_float(u2 & 0xFFFF0000u);
    const float l3 = v[3] - __uint_as_float(u3 & 0xFFFF0000u);
    bfr[0] = PACK_HI(u1, u0);                                      // hi0,hi1
    bfr[1] = PACK_HI(u3, u2);                                      // hi2,hi3
    bfr[2] = PACK_HI(__float_as_uint(l1), __float_as_uint(l0));    // lo0,lo1
    bfr[3] = PACK_HI(__float_as_uint(l3), __float_as_uint(l2));    // lo2,lo3
  };

  auto step = [&](const i32x4& a0, const i32x4& a1, float phx, float phy){
    i32x4 sw; sw[0]=bfr[2]; sw[1]=bfr[3]; sw[2]=bfr[0]; sw[3]=bfr[1];
    const bf16x8 bh = __builtin_bit_cast(bf16x8, bfr);
    const bf16x8 bs = __builtin_bit_cast(bf16x8, sw);
    f32x4 acc0 = {0.f,0.f,0.f,0.f};
    f32x4 acc1 = {0.f,0.f,0.f,0.f};
    acc0 = __builtin_amdgcn_mfma_f32_16x16x32_bf16(__builtin_bit_cast(bf16x8, a0), bh, acc0, 0,0,0);
    acc0 = __builtin_amdgcn_mfma_f32_16x16x32_bf16(__builtin_bit_cast(bf16x8, a0), bs, acc0, 0,0,0);
    acc1 = __builtin_amdgcn_mfma_f32_16x16x32_bf16(__builtin_bit_cast(bf16x8, a1), bh, acc1, 0,0,0);
    acc1 = __builtin_amdgcn_mfma_f32_16x16x32_bf16(__builtin_bit_cast(bf16x8, a1), bs, acc1, 0,0,0);
    v[0] = phx*acc0[0] + phy*acc1[0];
    v[1] = phx*acc0[1] + phy*acc1[1];
    v[2] = phx*acc0[2] + phy*acc1[2];
    v[3] = phx*acc0[3] + phy*acc1[3];
    make_bfrag();
  };

  if (isFwd){
    const i32x4* tab = ws;
    const float2 ph0 = *(const float2*)phiRow;    // phi[0]
    #pragma unroll
    for(int reg=0; reg<4; ++reg){
      const int r = g*4 + reg;
      v[reg] = ph0.x * core_first[r] + ph0.y * core_first[16 + r];
    }
    make_bfrag();
    i32x4 F0a = tab[lane],       F0b = tab[64 + lane];
    i32x4 F1a = tab[128 + lane], F1b = tab[192 + lane];
    i32x4 F2a = tab[256 + lane], F2b = tab[320 + lane];
    i32x4 F3a = tab[384 + lane], F3b = tab[448 + lane];
    float2 c0 = *(const float2*)(phiRow + 2);     // coeff(t) = phi[t+1]
    float2 c1 = *(const float2*)(phiRow + 4);
    float2 c2 = *(const float2*)(phiRow + 6);
    float2 c3 = *(const float2*)(phiRow + 8);
    #pragma unroll 1
    for(int t = 0; t < NFWD; t += 4){
      step(F0a, F0b, c0.x, c0.y);
      { const int sp = (t+4 < NFWD) ? (t+4) : (NFWD-1);
        F0a = tab[sp*128 + lane]; F0b = tab[sp*128 + 64 + lane];
        c0 = *(const float2*)(phiRow + 2*(t+5)); }
      step(F1a, F1b, c1.x, c1.y);
      { const int sp = (t+5 < NFWD) ? (t+5) : (NFWD-1);
        F1a = tab[sp*128 + lane]; F1b = tab[sp*128 + 64 + lane];
        c1 = *(const float2*)(phiRow + 2*(t+6)); }
      step(F2a, F2b, c2.x, c2.y);
      { const int sp = (t+6 < NFWD) ? (t+6) : (NFWD-1);
        F2a = tab[sp*128 + lane]; F2b = tab[sp*128 + 64 + lane];
        c2 = *(const float2*)(phiRow + 2*(t+7)); }
      step(F3a, F3b, c3.x, c3.y);
      { const int sp = (t+7 < NFWD) ? (t+7) : (NFWD-1);
        F3a = tab[sp*128 + lane]; F3b = tab[sp*128 + 64 + lane];
        c3 = *(const float2*)(phiRow + 2*(t+8)); }
    }
  } else {
    const i32x4* tab = ws + BWD_OFF;
    const float4 fL = *(const float4*)(phiRow + 508);  // idx254 (x,y) idx255 (z,w)
    #pragma unroll
    for(int reg=0; reg<4; ++reg){
      const int r = g*4 + reg;
      v[reg] = fL.z * core_last[2*r] + fL.w * core_last[2*r + 1];
    }
    make_bfrag();
    i32x4 F0a = tab[lane],       F0b = tab[64 + lane];
    i32x4 F1a = tab[128 + lane], F1b = tab[192 + lane];
    i32x4 F2a = tab[256 + lane], F2b = tab[320 + lane];
    i32x4 F3a = tab[384 + lane], F3b = tab[448 + lane];
    float2 c0 = make_float2(fL.x, fL.y);               // coeff(s) = phi[254-s]
    float2 c1 = *(const float2*)(phiRow + 2*253);
    float2 c2 = *(const float2*)(phiRow + 2*252);
    float2 c3 = *(const float2*)(phiRow + 2*251);
    #pragma unroll 1
    for(int s = 0; s < 124; s += 4){
      step(F0a, F0b, c0.x, c0.y);
      { const int sp = (s+4 < NBWD) ? (s+4) : (NBWD-1);
        F0a = tab[sp*128 + lane]; F0b = tab[sp*128 + 64 + lane];
        c0 = *(const float2*)(phiRow + 2*(250-s)); }
      step(F1a, F1b, c1.x, c1.y);
      { const int sp = (s+5 < NBWD) ? (s+5) : (NBWD-1);
        F1a = tab[sp*128 + lane]; F1b = tab[sp*128 + 64 + lane];
        c1 = *(const float2*)(phiRow + 2*(249-s)); }
      step(F2a, F2b, c2.x, c2.y);
      { const int sp = (s+6 < NBWD) ? (s+6) : (NBWD-1);
        F2a = tab[sp*128 + lane]; F2b = tab[sp*128 + 64 + lane];
        c2 = *(const float2*)(phiRow + 2*(248-s)); }
      step(F3a, F3b, c3.x, c3.y);
      { const int sp = (s+7 < NBWD) ? (s+7) : (NBWD-1);
        F3a = tab[sp*128 + lane]; F3b = tab[sp*128 + 64 + lane];
        c3 = *(const float2*)(phiRow + 2*(247-s)); }
    }
    step(F0a, F0b, c0.x, c0.y);   // s=124
    step(F1a, F1b, c1.x, c1.y);   // s=125
  }

  // epilogue: deposit f / b, block dot
  *(float4*)&red[isFwd ? 0 : 1][s_in][4*g] = make_float4(v[0], v[1], v[2], v[3]);
  __syncthreads();
  if (threadIdx.x < 32){
    const int s = threadIdx.x;
    float acc = bias[0];
    #pragma unroll
    for(int q = 0; q < 16; ++q)
      acc += red[0][s][q] * red[1][s][q];
    out[b0 + s] = acc;
  }
}

extern "C" void kernel_launch(void* const* d_in, const int* in_sizes, int n_in,
                              void* d_out, int out_size, void* d_ws, size_t ws_size,
                              hipStream_t stream)
{
  const float* phi  = (const float*)d_in[0];  // [32768,256,2]
  const float* cf   = (const float*)d_in[1];  // [2,16]
  const float* cm   = (const float*)d_in[2];  // [254,16,2,16]
  const float* cl   = (const float*)d_in[3];  // [16,2]
  const float* bias = (const float*)d_in[4];  // scalar
  i32x4* ws = (i32x4*)d_ws;                   // (128+126)*2*64*16B = 508 KB

  build_frags<<<254, 128, 0, stream>>>(cm, ws);
  mps_chain<<<1024, 256, 0, stream>>>(phi, cf, cl, bias, ws, (float*)d_out);
}

// Round 6
// 142.633 us; speedup vs baseline: 1.1258x; 1.1220x over previous
//
#include <hip/hip_runtime.h>
#include <stdint.h>

// MPS chain contraction, B=32768, L=256, D=16 — bidirectional split +
// permutation-absorbed B layout + LDS double-buffered chunk pipeline.
//
// R1-R5 lesson: register-resident prefetch pipelines collapse (compiler
// schedules loads at use, VGPR=36), exposing L2/HBM latency per serial step
// (~90us plateau). R6 moves ALL steady-state global traffic into
// global_load_lds DMA per 4-step chunk, double-buffered, barrier-drained.
// The chain touches only LDS (ds_read_b128 frags, ds_read_b64 phi broadcast).
//
// Math (unchanged from R4, absmax 4.24e-22):
//   out = v0^T M_0..M_253 z = f.b ; fwd 128 steps, bwd 126 (padded to 128).
//   Step: C[m][n] = sum_k A_p[m][k] B[k][n]; B K-mapping defined so the
//   next B operand is built per-lane from the accumulator (and/sub/perm).
//   A x B + A x Bswap({2,3,0,1}) = (ch+cl)(vh+vl) exactly.

typedef short  bf16x8 __attribute__((ext_vector_type(8)));
typedef float  f32x4  __attribute__((ext_vector_type(4)));
typedef int    i32x4  __attribute__((ext_vector_type(4)));
typedef unsigned int u32;

#define NSLOT 128              // slots per direction (bwd 126 padded to 128)
#define BWD_OFF (NSLOT*2*64)   // i32x4 units
#define NCHUNK 32              // 4 steps per chunk

#define PACK_HI(hi, lo) ((int)__builtin_amdgcn_perm((u32)(hi), (u32)(lo), 0x07060302u))

__device__ __forceinline__ u32 rne_bump(u32 u){
  return u + 0x7FFFu + ((u >> 16) & 1u);
}

// async global->LDS DMA, 16B per lane, lands at (uniform base) + lane*16
__device__ __forceinline__ void async16(const void* g, void* l){
  __builtin_amdgcn_global_load_lds(
    (const __attribute__((address_space(1))) u32*)(uintptr_t)g,
    (__attribute__((address_space(3))) u32*)(uintptr_t)l, 16, 0, 0);
}

// A-frag table. lane (m=lane&15, g=lane>>4) holds k=8g+j, j=0..7 packed
// 2 bf16/dword; q = 4g+(j&3), hi part iff j<4.
// fwd slot t: c_p[m][q] = cm[t][q][p][m]; bwd slot s (t=253-s): cm[t][m][p][q].
__global__ void build_frags(const float* __restrict__ cm, i32x4* __restrict__ ws)
{
  const int bid  = blockIdx.x;          // 0..127 fwd, 128..255 bwd
  const int p    = threadIdx.x >> 6;    // block = 128 threads
  const int lane = threadIdx.x & 63;
  const int m    = lane & 15;
  const int g    = lane >> 4;
  const bool fwd = bid < NSLOT;
  const int slot = fwd ? bid : (bid - NSLOT);
  const int t    = fwd ? bid : (253 - slot);   // slots 126,127 bwd: dummies
  i32x4* dst = ws + (fwd ? 0 : BWD_OFF) + (slot*2 + p)*64 + lane;
  i32x4 w;
  #pragma unroll
  for(int d=0; d<4; ++d){
    u32 h[2];
    #pragma unroll
    for(int e=0; e<2; ++e){
      const int j = 2*d + e;
      const int q = 4*g + (j & 3);
      const bool hi_part = (j < 4);
      const int ci = fwd ? ((((t*16 + q)*2) + p)*16 + m)
                         : ((((t*16 + m)*2) + p)*16 + q);
      const float c = cm[ci];
      const u32 u  = __float_as_uint(c);
      const u32 a  = rne_bump(u);
      const float hif = __uint_as_float(a & 0xFFFF0000u);
      const u32 b  = rne_bump(__float_as_uint(c - hif));
      h[e] = hi_part ? (a >> 16) : (b >> 16);
    }
    w[d] = (int)(h[0] | (h[1] << 16));
  }
  *dst = w;
}

__global__ __launch_bounds__(256, 4) void mps_chain(
  const float* __restrict__ phi,
  const float* __restrict__ core_first,
  const float* __restrict__ core_last,
  const float* __restrict__ bias,
  const i32x4* __restrict__ ws,
  float* __restrict__ out)
{
  const int lane = threadIdx.x & 63;
  const int wv   = threadIdx.x >> 6;
  const int b0   = blockIdx.x * 32;
  const int n    = lane & 15;            // sample column
  const int g    = lane >> 4;            // holds rows 4g..4g+3
  const int half = wv & 1;
  const int s_in = half*16 + n;
  const bool isFwd = (wv < 2);

  // LDS: 16K + 16K + 4K + 4K = 40960 B -> exactly 4 blocks/CU
  __shared__ i32x4 fragF[2][4][2][64];   // [buf][slot-in-chunk][p][lane]
  __shared__ i32x4 fragB[2][4][2][64];
  __shared__ float2 phF[2][2][64][2];    // [buf][call][dma-lane][pair]
  __shared__ float2 phB[2][2][64][2];

  const float* phiRow = phi + (size_t)(b0 + s_in) * 512;

  // per-lane DMA gather base for phi: sample b0+half*16+(l>>2), quarter l&3
  const float* phiDmaBase = phi + (size_t)(b0 + half*16 + (lane >> 2)) * 512
                                + (lane & 3) * 4;
  const i32x4* wsD = isFwd ? ws : (ws + BWD_OFF);

  // issue all DMAs for chunk c into buffer buf (5 calls/wave, uniform flow)
  auto issue_dma = [&](int c, int buf){
    #pragma unroll
    for (int jj = 0; jj < 2; ++jj){
      const int j = half*2 + jj;
      const int slot = c*4 + j;
      #pragma unroll
      for (int p = 0; p < 2; ++p){
        const i32x4* gp = wsD + (slot*2 + p)*64 + lane;
        void* lp = isFwd ? (void*)&fragF[buf][j][p][0]
                         : (void*)&fragB[buf][j][p][0];
        async16(gp, lp);
      }
    }
    const int w = isFwd ? 4*c : (248 - 4*c);   // 8-idx aligned phi window
    const float* gp = phiDmaBase + 2*w;
    void* lp = isFwd ? (void*)&phF[buf][half][0][0]
                     : (void*)&phB[buf][half][0][0];
    async16(gp, lp);
  };

  float v[4];
  i32x4 bfr;

  auto make_bfrag = [&](){
    const u32 u0 = __float_as_uint(v[0]), u1 = __float_as_uint(v[1]);
    const u32 u2 = __float_as_uint(v[2]), u3 = __float_as_uint(v[3]);
    const float l0 = v[0] - __uint_as_float(u0 & 0xFFFF0000u);
    const float l1 = v[1] - __uint_as_float(u1 & 0xFFFF0000u);
    const float l2 = v[2] - __uint_as_float(u2 & 0xFFFF0000u);
    const float l3 = v[3] - __uint_as_float(u3 & 0xFFFF0000u);
    bfr[0] = PACK_HI(u1, u0);
    bfr[1] = PACK_HI(u3, u2);
    bfr[2] = PACK_HI(__float_as_uint(l1), __float_as_uint(l0));
    bfr[3] = PACK_HI(__float_as_uint(l3), __float_as_uint(l2));
  };

  auto step = [&](const i32x4& a0, const i32x4& a1, float phx, float phy){
    i32x4 sw; sw[0]=bfr[2]; sw[1]=bfr[3]; sw[2]=bfr[0]; sw[3]=bfr[1];
    const bf16x8 bh = __builtin_bit_cast(bf16x8, bfr);
    const bf16x8 bs = __builtin_bit_cast(bf16x8, sw);
    f32x4 acc0 = {0.f,0.f,0.f,0.f};
    f32x4 acc1 = {0.f,0.f,0.f,0.f};
    acc0 = __builtin_amdgcn_mfma_f32_16x16x32_bf16(__builtin_bit_cast(bf16x8, a0), bh, acc0, 0,0,0);
    acc0 = __builtin_amdgcn_mfma_f32_16x16x32_bf16(__builtin_bit_cast(bf16x8, a0), bs, acc0, 0,0,0);
    acc1 = __builtin_amdgcn_mfma_f32_16x16x32_bf16(__builtin_bit_cast(bf16x8, a1), bh, acc1, 0,0,0);
    acc1 = __builtin_amdgcn_mfma_f32_16x16x32_bf16(__builtin_bit_cast(bf16x8, a1), bs, acc1, 0,0,0);
    v[0] = phx*acc0[0] + phy*acc1[0];
    v[1] = phx*acc0[1] + phy*acc1[1];
    v[2] = phx*acc0[2] + phy*acc1[2];
    v[3] = phx*acc0[3] + phy*acc1[3];
    make_bfrag();
  };

  // ---- init state (prologue, register loads are fine here) ----
  if (isFwd){
    const float2 ph0 = *(const float2*)phiRow;               // phi[0]
    #pragma unroll
    for(int reg=0; reg<4; ++reg){
      const int r = g*4 + reg;
      v[reg] = ph0.x * core_first[r] + ph0.y * core_first[16 + r];
    }
  } else {
    const float4 fL = *(const float4*)(phiRow + 508);        // phi[254],[255]
    #pragma unroll
    for(int reg=0; reg<4; ++reg){
      const int r = g*4 + reg;
      v[reg] = fL.z * core_last[2*r] + fL.w * core_last[2*r + 1];
    }
  }
  make_bfrag();

  issue_dma(0, 0);
  __syncthreads();

  const int limit = isFwd ? 128 : 126;
  const i32x4 (*fragD)[4][2][64] = isFwd ? fragF : fragB;
  const float2 (*phD)[2][64][2]  = isFwd ? phF : phB;

  #pragma unroll 1
  for (int c = 0; c < NCHUNK; ++c){
    const int buf = c & 1;
    if (c + 1 < NCHUNK) issue_dma(c + 1, buf ^ 1);
    #pragma unroll
    for (int i = 0; i < 4; ++i){
      if (c*4 + i < limit){                       // wave-uniform (bwd tail)
        const int o = isFwd ? (1 + i) : (6 - i);  // offset in 8-idx window
        const float2 ph = phD[buf][half][n*4 + (o >> 1)][o & 1];
        const i32x4 a0 = fragD[buf][i][0][lane];
        const i32x4 a1 = fragD[buf][i][1][lane];
        step(a0, a1, ph.x, ph.y);
      }
    }
    __syncthreads();   // drains next chunk's DMA; releases this buffer
  }

  // ---- epilogue: reuse fragF LDS as reduction buffer ----
  float* red = (float*)&fragF[0][0][0][0];       // 64 rows x 20 floats
  *(float4*)&red[((isFwd ? 0 : 1)*32 + s_in)*20 + 4*g] =
      make_float4(v[0], v[1], v[2], v[3]);
  __syncthreads();
  if (threadIdx.x < 32){
    const int s = threadIdx.x;
    float acc = bias[0];
    #pragma unroll
    for(int q = 0; q < 16; ++q)
      acc += red[s*20 + q] * red[(32 + s)*20 + q];
    out[b0 + s] = acc;
  }
}

extern "C" void kernel_launch(void* const* d_in, const int* in_sizes, int n_in,
                              void* d_out, int out_size, void* d_ws, size_t ws_size,
                              hipStream_t stream)
{
  const float* phi  = (const float*)d_in[0];  // [32768,256,2]
  const float* cf   = (const float*)d_in[1];  // [2,16]
  const float* cm   = (const float*)d_in[2];  // [254,16,2,16]
  const float* cl   = (const float*)d_in[3];  // [16,2]
  const float* bias = (const float*)d_in[4];  // scalar
  i32x4* ws = (i32x4*)d_ws;                   // 2*128*2*64*16B = 512 KB

  build_frags<<<256, 128, 0, stream>>>(cm, ws);
  mps_chain<<<1024, 256, 0, stream>>>(phi, cf, cl, bias, ws, (float*)d_out);
}

// Round 7
// 138.002 us; speedup vs baseline: 1.1635x; 1.0336x over previous
//
#include <hip/hip_runtime.h>
#include <stdint.h>

// MPS chain contraction, B=32768, L=256, D=16.
// R7: CORE PAIRING on the R6 LDS-DMA structure.
//   Pair product: M_t M_{t+1} = sum_pq phi[t+1][p] phi[t+2][q] C_{t,p} C_{t+1,q}
//   Prologue precomputes G_pq (f32 16x16 products) per pair, RNE hi/lo split
//   into A-fragments with the permutation-absorbed K mapping (k=8g+j ->
//   col 4g+(j&3), hi iff j<4) so the next B operand is built per-lane
//   from the accumulator (and/sub/perm only; swap = dword rotate).
//   Exact per pair: A x B + A x Bswap = (Gh+Gl)(vh+vl).
// fwd: 64 pairs (t=0..127); bwd: 63 pairs (t=253..128). 2 pairs/chunk,
// 32 chunks, double-buffered global_load_lds DMA, 4 blocks/CU (40KB LDS).

typedef short  bf16x8 __attribute__((ext_vector_type(8)));
typedef float  f32x4  __attribute__((ext_vector_type(4)));
typedef int    i32x4  __attribute__((ext_vector_type(4)));
typedef unsigned int u32;

#define NPF 64
#define NPB 63
#define BWD_OFF (NPF*4*64)   // i32x4 units
#define NCHUNK 32

#define PACK_HI(hi, lo) ((int)__builtin_amdgcn_perm((u32)(hi), (u32)(lo), 0x07060302u))

__device__ __forceinline__ u32 rne_bump(u32 u){ return u + 0x7FFFu + ((u >> 16) & 1u); }

__device__ __forceinline__ void async16(const void* g, void* l){
  __builtin_amdgcn_global_load_lds(
    (const __attribute__((address_space(1))) u32*)(uintptr_t)g,
    (__attribute__((address_space(3))) u32*)(uintptr_t)l, 16, 0, 0);
}

// Pair-fragment table: blocks 0..63 fwd (j=bid), 64..126 bwd (j=bid-64).
// fwd: G[m][cq] = sum_r Ca[cq][p][r]*Cb[r][q][m],  Ca=cm[2j], Cb=cm[2j+1]
// bwd: G[m][cq] = sum_r Ca[m][p][r]*Cb[r][q][cq],  Ca=cm[252-2j], Cb=cm[253-2j]
// lane (m=lane&15, g=lane>>4) packs cols 4g..4g+3 hi (dw0,1) and lo (dw2,3).
__global__ void build_pair_frags(const float* __restrict__ cm, i32x4* __restrict__ ws)
{
  __shared__ float Ca[512], Cb[512];   // [x][p][y] = cm[t][x][p][y]
  const int bid = blockIdx.x;
  const bool fwd = bid < NPF;
  const int j  = fwd ? bid : bid - NPF;
  const int ta = fwd ? 2*j     : 252 - 2*j;
  const int tb = fwd ? 2*j + 1 : 253 - 2*j;
  {
    const float* A = cm + ta*512;
    const float* B = cm + tb*512;
    for (int i = threadIdx.x; i < 512; i += 256){ Ca[i] = A[i]; Cb[i] = B[i]; }
  }
  __syncthreads();
  const int f    = threadIdx.x >> 6;    // combo p*2+q
  const int lane = threadIdx.x & 63;
  const int m    = lane & 15;
  const int g    = lane >> 4;
  const int p    = f >> 1, q = f & 1;
  u32 hi[4], lo[4];
  #pragma unroll
  for (int x = 0; x < 4; ++x){
    const int cq = 4*g + x;
    float acc = 0.f;
    #pragma unroll
    for (int r = 0; r < 16; ++r){
      const float a = fwd ? Ca[cq*32 + p*16 + r] : Ca[m*32 + p*16 + r];
      const float b = fwd ? Cb[r*32 + q*16 + m]  : Cb[r*32 + q*16 + cq];
      acc = fmaf(a, b, acc);
    }
    const u32 u  = __float_as_uint(acc);
    const u32 aa = rne_bump(u);
    const float hf = __uint_as_float(aa & 0xFFFF0000u);
    const u32 bb = rne_bump(__float_as_uint(acc - hf));
    hi[x] = aa >> 16; lo[x] = bb >> 16;
  }
  i32x4 w;
  w[0] = (int)(hi[0] | (hi[1] << 16));
  w[1] = (int)(hi[2] | (hi[3] << 16));
  w[2] = (int)(lo[0] | (lo[1] << 16));
  w[3] = (int)(lo[2] | (lo[3] << 16));
  ws[(fwd ? 0 : BWD_OFF) + (j*4 + f)*64 + lane] = w;
}

__global__ __launch_bounds__(256, 4) void mps_chain(
  const float* __restrict__ phi,
  const float* __restrict__ core_first,
  const float* __restrict__ core_last,
  const float* __restrict__ bias,
  const i32x4* __restrict__ ws,
  float* __restrict__ out)
{
  const int lane = threadIdx.x & 63;
  const int wv   = threadIdx.x >> 6;
  const int b0   = blockIdx.x * 32;
  const int n    = lane & 15;            // sample column
  const int g    = lane >> 4;            // holds rows 4g..4g+3
  const int half = wv & 1;
  const int s_in = half*16 + n;
  const bool isFwd = (wv < 2);
  const int dirIdx = isFwd ? 0 : 1;

  // LDS: frags 32 KB + phi 8 KB = 40 KB -> 4 blocks/CU
  __shared__ i32x4 frag[2][2][2][4][64];     // [dir][buf][pairInChunk][combo][lane]
  __shared__ float phL[2][2][2][4][16][4];   // [dir][buf][k=half][qt][sloc][e]

  const float* phiRow = phi + (size_t)(b0 + s_in) * 512;

  // phi DMA source (transposed lane map: sloc=lane&15 -> sample, qt=lane>>4)
  const float* phiDma = phi + (size_t)(b0 + 16*half + (lane & 15)) * 512
                            + (lane >> 4) * 4;
  const i32x4* wsD = isFwd ? ws : (ws + BWD_OFF);

  auto issue_dma = [&](int cn, int buf){
    int pr = 2*cn + half;
    if (!isFwd && pr > NPB-1) pr = NPB-1;        // clamp dummy (compute skipped)
    const i32x4* base = wsD + pr*4*64 + lane;
    #pragma unroll
    for (int f = 0; f < 4; ++f)
      async16(base + f*64, &frag[dirIdx][buf][half][f][0]);
    const int W = isFwd ? 4*cn : (248 - 4*cn);   // 8-idx window start
    async16(phiDma + 2*W, &phL[dirIdx][buf][half][0][0][0]);
  };

  float v[4];
  i32x4 bfr;

  auto make_bfrag = [&](){
    const u32 u0 = __float_as_uint(v[0]), u1 = __float_as_uint(v[1]);
    const u32 u2 = __float_as_uint(v[2]), u3 = __float_as_uint(v[3]);
    const float l0 = v[0] - __uint_as_float(u0 & 0xFFFF0000u);
    const float l1 = v[1] - __uint_as_float(u1 & 0xFFFF0000u);
    const float l2 = v[2] - __uint_as_float(u2 & 0xFFFF0000u);
    const float l3 = v[3] - __uint_as_float(u3 & 0xFFFF0000u);
    bfr[0] = PACK_HI(u1, u0);
    bfr[1] = PACK_HI(u3, u2);
    bfr[2] = PACK_HI(__float_as_uint(l1), __float_as_uint(l0));
    bfr[3] = PACK_HI(__float_as_uint(l3), __float_as_uint(l2));
  };

  auto pair_step = [&](const i32x4& G0, const i32x4& G1, const i32x4& G2,
                       const i32x4& G3, float2 cA, float2 cB){
    const float c00 = cA.x*cB.x, c01 = cA.x*cB.y;
    const float c10 = cA.y*cB.x, c11 = cA.y*cB.y;
    i32x4 sw; sw[0]=bfr[2]; sw[1]=bfr[3]; sw[2]=bfr[0]; sw[3]=bfr[1];
    const bf16x8 bh = __builtin_bit_cast(bf16x8, bfr);
    const bf16x8 bs = __builtin_bit_cast(bf16x8, sw);
    const f32x4 z = {0.f,0.f,0.f,0.f};
    f32x4 a00 = __builtin_amdgcn_mfma_f32_16x16x32_bf16(__builtin_bit_cast(bf16x8,G0), bh, z, 0,0,0);
    a00 = __builtin_amdgcn_mfma_f32_16x16x32_bf16(__builtin_bit_cast(bf16x8,G0), bs, a00, 0,0,0);
    f32x4 a01 = __builtin_amdgcn_mfma_f32_16x16x32_bf16(__builtin_bit_cast(bf16x8,G1), bh, z, 0,0,0);
    a01 = __builtin_amdgcn_mfma_f32_16x16x32_bf16(__builtin_bit_cast(bf16x8,G1), bs, a01, 0,0,0);
    f32x4 a10 = __builtin_amdgcn_mfma_f32_16x16x32_bf16(__builtin_bit_cast(bf16x8,G2), bh, z, 0,0,0);
    a10 = __builtin_amdgcn_mfma_f32_16x16x32_bf16(__builtin_bit_cast(bf16x8,G2), bs, a10, 0,0,0);
    f32x4 a11 = __builtin_amdgcn_mfma_f32_16x16x32_bf16(__builtin_bit_cast(bf16x8,G3), bh, z, 0,0,0);
    a11 = __builtin_amdgcn_mfma_f32_16x16x32_bf16(__builtin_bit_cast(bf16x8,G3), bs, a11, 0,0,0);
    #pragma unroll
    for (int i2 = 0; i2 < 4; ++i2)
      v[i2] = c00*a00[i2] + c01*a01[i2] + c10*a10[i2] + c11*a11[i2];
    make_bfrag();
  };

  // ---- init ----
  if (isFwd){
    const float2 ph0 = *(const float2*)phiRow;               // phi[0]
    #pragma unroll
    for (int reg = 0; reg < 4; ++reg){
      const int r = g*4 + reg;
      v[reg] = ph0.x * core_first[r] + ph0.y * core_first[16 + r];
    }
  } else {
    const float2 phL2 = *(const float2*)(phiRow + 510);      // phi[255]
    #pragma unroll
    for (int reg = 0; reg < 4; ++reg){
      const int r = g*4 + reg;
      v[reg] = phL2.x * core_last[2*r] + phL2.y * core_last[2*r + 1];
    }
  }
  make_bfrag();

  issue_dma(0, 0);
  __syncthreads();

  #pragma unroll 1
  for (int c = 0; c < NCHUNK; ++c){
    const int buf = c & 1;
    if (c + 1 < NCHUNK) issue_dma(c + 1, buf ^ 1);

    // coefficients from staged phi window (f[idx] = pb[ (idx>>2)*64 + (idx&3) ])
    const float* pb = &phL[dirIdx][buf][half][0][n][0];
    const float2 xA0 = *(const float2*)(pb + (isFwd ?   2 : 130));  // f2,3 | f10,11
    const float2 xB0 = *(const float2*)(pb + (isFwd ?  64 : 192));  // f4,5 | f12,13
    const float2 xA1 = *(const float2*)(pb + 66);                   // f6,7
    const float2 xB1 = *(const float2*)(pb + 128);                  // f8,9

    {
      const i32x4 G0 = frag[dirIdx][buf][0][0][lane];
      const i32x4 G1 = frag[dirIdx][buf][0][1][lane];
      const i32x4 G2 = frag[dirIdx][buf][0][2][lane];
      const i32x4 G3 = frag[dirIdx][buf][0][3][lane];
      pair_step(G0, G1, G2, G3, xA0, xB0);
    }
    if (isFwd || (2*c + 1) < NPB){
      const i32x4 G0 = frag[dirIdx][buf][1][0][lane];
      const i32x4 G1 = frag[dirIdx][buf][1][1][lane];
      const i32x4 G2 = frag[dirIdx][buf][1][2][lane];
      const i32x4 G3 = frag[dirIdx][buf][1][3][lane];
      pair_step(G0, G1, G2, G3, xA1, xB1);
    }
    __syncthreads();
  }

  // ---- epilogue: reuse frag LDS as reduction buffer ----
  float* red = (float*)&frag[0][0][0][0][0];     // 64 rows x 20 floats
  *(float4*)&red[(dirIdx*32 + s_in)*20 + 4*g] =
      make_float4(v[0], v[1], v[2], v[3]);
  __syncthreads();
  if (threadIdx.x < 32){
    const int s = threadIdx.x;
    float acc = bias[0];
    #pragma unroll
    for (int qq = 0; qq < 16; ++qq)
      acc += red[s*20 + qq] * red[(32 + s)*20 + qq];
    out[b0 + s] = acc;
  }
}

extern "C" void kernel_launch(void* const* d_in, const int* in_sizes, int n_in,
                              void* d_out, int out_size, void* d_ws, size_t ws_size,
                              hipStream_t stream)
{
  const float* phi  = (const float*)d_in[0];  // [32768,256,2]
  const float* cf   = (const float*)d_in[1];  // [2,16]
  const float* cm   = (const float*)d_in[2];  // [254,16,2,16]
  const float* cl   = (const float*)d_in[3];  // [16,2]
  const float* bias = (const float*)d_in[4];  // scalar
  i32x4* ws = (i32x4*)d_ws;                   // (64+63)*4*64*16B = 508 KB

  build_pair_frags<<<NPF + NPB, 256, 0, stream>>>(cm, ws);
  mps_chain<<<1024, 256, 0, stream>>>(phi, cf, cl, bias, ws, (float*)d_out);
}